// Round 1
// baseline (271.679 us; speedup 1.0000x reference)
//
#include <hip/hip_runtime.h>
#include <math.h>

// CapsuleLinear dynamic routing, `priors` never materialized.
//   s[b,o,i]   = sum_n prob[b,o,n] * x[b,n,i]
//   out[b,o,l] = sum_i W[o,l,i] * s[b,o,i]
//   logits[b,o,n] = x[b,n,:] . T[b,o,:],  T accumulates t_r[o,i] = sum_l W[o,l,i]*v_r[o,l]
//
// R1 restructure: last-block-ticket fusion. The per-batch vt reduction
// (reduce partials -> u -> squash -> T/out) is inlined into the block of
// batch b that draws atomic ticket 15, instead of a separate 32-block
// kernel. Chain: k_init -> k_pass_vt -> k_pass_vt(final)  (5 -> 3 launches,
// vt tails overlap with other batches' pass work).

#define N_B      32
#define IN_CAPS  1152
#define IN_LEN   32
#define OUT_CAPS 64
#define OUT_LEN  32

#define NCHUNK 16                    // n-chunks per batch -> 32*16 = 512 blocks
#define NPB    (IN_CAPS / NCHUNK)    // 72 n per block
#define PASS_WAVES 4                 // 256-thread blocks
#define NPW    (NPB / PASS_WAVES)    // 18 n per wave

// ---------------------------------------------------------------------------
// k_init: s0[i] = (1/64) sum_n x[b,n,i]; u = W@s0; v0 = squash(u); T = W^T@v0
//         Also zeroes the ticket counters for both k_pass_vt launches
//         (ws is poisoned between runs; counters must be re-armed each launch).
// ---------------------------------------------------------------------------
__global__ __launch_bounds__(256) void k_init(const float* __restrict__ x,
                                              const float* __restrict__ W,
                                              float* __restrict__ T,
                                              int* __restrict__ cnt) {
    const int b   = blockIdx.x;
    const int tid = threadIdx.x;
    if (tid == 0) { cnt[b] = 0; cnt[N_B + b] = 0; }
    const float* xb = x + (size_t)b * IN_CAPS * IN_LEN;

    // --- reduce x over n (coalesced float4) ---
    __shared__ float4 red4[32][8];
    {
        const int q = tid & 7;        // float4 column (8 per row of 32)
        const int g = tid >> 3;       // 0..31 n-offset
        float4 acc = make_float4(0.f, 0.f, 0.f, 0.f);
        for (int n = g; n < IN_CAPS; n += 32) {
            const float4 v = *(const float4*)(xb + n * IN_LEN + q * 4);
            acc.x += v.x; acc.y += v.y; acc.z += v.z; acc.w += v.w;
        }
        red4[g][q] = acc;
    }
    __syncthreads();
    __shared__ float s0[IN_LEN];
    if (tid < 8) {
        float4 v = make_float4(0.f, 0.f, 0.f, 0.f);
        for (int g = 0; g < 32; ++g) {
            const float4 r = red4[g][tid];
            v.x += r.x; v.y += r.y; v.z += r.z; v.w += r.w;
        }
        const float inv = 1.f / 64.f;   // uniform softmax prob at r=0
        s0[tid * 4 + 0] = v.x * inv;
        s0[tid * 4 + 1] = v.y * inv;
        s0[tid * 4 + 2] = v.z * inv;
        s0[tid * 4 + 3] = v.w * inv;
    }
    __syncthreads();

    // --- u[o][l] = sum_i W[o,l,i] * s0[i] ---
    __shared__ float u[OUT_CAPS * OUT_LEN];
    for (int e = tid; e < OUT_CAPS * OUT_LEN; e += 256) {
        const float* wrow = W + (size_t)e * IN_LEN;
        float a = 0.f;
#pragma unroll
        for (int i = 0; i < IN_LEN; ++i) a = fmaf(wrow[i], s0[i], a);
        u[e] = a;
    }
    __syncthreads();

    // --- squash scale per o ---
    __shared__ float scale[OUT_CAPS];
    if (tid < OUT_CAPS) {
        float ns = 0.f;
#pragma unroll
        for (int l = 0; l < OUT_LEN; ++l) { const float v = u[tid * OUT_LEN + l]; ns = fmaf(v, v, ns); }
        scale[tid] = sqrtf(ns) / (1.f + ns);
    }
    __syncthreads();

    // --- T[b,o,i] = sum_l W[o,l,i] * (u[o,l]*scale[o]) ---
    for (int e = tid; e < OUT_CAPS * IN_LEN; e += 256) {
        const int o = e >> 5, i = e & 31;
        float a = 0.f;
#pragma unroll
        for (int l = 0; l < OUT_LEN; ++l)
            a = fmaf(W[((size_t)o * OUT_LEN + l) * IN_LEN + i], u[o * OUT_LEN + l], a);
        T[(size_t)b * OUT_CAPS * IN_LEN + e] = a * scale[o];
    }
}

// ---------------------------------------------------------------------------
// k_pass_vt: per (b, n-chunk): logit[o]=x.T[o]; softmax over o (lane=o);
//            s_partial[o,i] += prob[o]*x[i] -> part[b,c,:].
//            Then ticket: the 16th block of batch b inlines the vt step:
//            s = sum_c part; u = W@s; squash; final ? out : T += W^T@v.
// ---------------------------------------------------------------------------
__global__ __launch_bounds__(256) void k_pass_vt(const float* __restrict__ x,
                                                 const float* __restrict__ W,
                                                 float* __restrict__ T,
                                                 float* __restrict__ part,
                                                 int* __restrict__ cnt,
                                                 float* __restrict__ out,
                                                 int final_iter) {
    const int b    = blockIdx.x >> 4;     // / NCHUNK
    const int c    = blockIdx.x & (NCHUNK - 1);
    const int lane = threadIdx.x & 63;    // = output capsule o
    const int wave = __builtin_amdgcn_readfirstlane(threadIdx.x >> 6);
    const int tid  = threadIdx.x;

    // lane-private T row and s accumulator (32 VGPRs each)
    float t[IN_LEN], s[IN_LEN];
    {
        const float* Trow = T + ((size_t)b * OUT_CAPS + lane) * IN_LEN;
#pragma unroll
        for (int i = 0; i < IN_LEN; ++i) { t[i] = Trow[i]; s[i] = 0.f; }
    }

    const float* xb = x + ((size_t)b * IN_CAPS + c * NPB + wave * NPW) * IN_LEN;
    for (int j = 0; j < NPW; ++j) {
        const float* xn = xb + j * IN_LEN;   // wave-uniform address
        float xv[IN_LEN];
#pragma unroll
        for (int i = 0; i < IN_LEN; ++i) xv[i] = xn[i];

        float logit = 0.f;
#pragma unroll
        for (int i = 0; i < IN_LEN; ++i) logit = fmaf(xv[i], t[i], logit);

        // softmax over the 64 lanes (= 64 output capsules)
        float m = logit;
#pragma unroll
        for (int off = 32; off >= 1; off >>= 1) m = fmaxf(m, __shfl_xor(m, off, 64));
        const float p = __expf(logit - m);
        float sum = p;
#pragma unroll
        for (int off = 32; off >= 1; off >>= 1) sum += __shfl_xor(sum, off, 64);
        const float prob = p / sum;

#pragma unroll
        for (int i = 0; i < IN_LEN; ++i) s[i] = fmaf(prob, xv[i], s[i]);
    }

    // reduce the 4 wave partials via LDS, write block partial to global
    __shared__ __align__(16) float sp[PASS_WAVES * OUT_CAPS * IN_LEN]; // 32 KB
    {
        float4* dst = (float4*)&sp[(wave * OUT_CAPS + lane) * IN_LEN];
#pragma unroll
        for (int q = 0; q < 8; ++q)
            dst[q] = make_float4(s[4 * q], s[4 * q + 1], s[4 * q + 2], s[4 * q + 3]);
    }
    __syncthreads();
    {
        const float4* sp4 = (const float4*)sp;
        float4* pb4 = (float4*)(part + ((size_t)b * NCHUNK + c) * OUT_CAPS * IN_LEN);
        for (int e = tid; e < OUT_CAPS * IN_LEN / 4; e += 256) {
            const float4 a0 = sp4[e];
            const float4 a1 = sp4[512 + e];
            const float4 a2 = sp4[1024 + e];
            const float4 a3 = sp4[1536 + e];
            pb4[e] = make_float4(a0.x + a1.x + a2.x + a3.x,
                                 a0.y + a1.y + a2.y + a3.y,
                                 a0.z + a1.z + a2.z + a3.z,
                                 a0.w + a1.w + a2.w + a3.w);
        }
    }

    // ---- ticket: last block of batch b performs the vt step ----
    __threadfence();                // make this block's part[] writes visible
    __syncthreads();                // all threads fenced before the ticket
    __shared__ int last_flag;
    if (tid == 0) last_flag = (atomicAdd(&cnt[b], 1) == NCHUNK - 1);
    __syncthreads();
    if (!last_flag) return;
    __threadfence();                // acquire: other blocks' part[] writes

    // vt scratch carved out of sp (all pass-phase reads of sp are done)
    float* s_lds = sp;                       // 2048 floats
    float* u     = sp + OUT_CAPS * IN_LEN;   // 2048 floats
    float* scale = sp + 2 * OUT_CAPS * IN_LEN; // 64 floats

    // s = sum_c part[b,c,:]
    {
        const float4* pb4 = (const float4*)(part + (size_t)b * NCHUNK * OUT_CAPS * IN_LEN);
        for (int e = tid; e < OUT_CAPS * IN_LEN / 4; e += 256) {
            float4 acc = make_float4(0.f, 0.f, 0.f, 0.f);
#pragma unroll
            for (int c2 = 0; c2 < NCHUNK; ++c2) {
                const float4 v = pb4[c2 * (OUT_CAPS * IN_LEN / 4) + e];
                acc.x += v.x; acc.y += v.y; acc.z += v.z; acc.w += v.w;
            }
            ((float4*)s_lds)[e] = acc;
        }
    }
    __syncthreads();

    // u[o,l] = sum_i W[o,l,i] * s[o,i]
    for (int e = tid; e < OUT_CAPS * OUT_LEN; e += 256) {
        const int o = e >> 5;
        const float* wrow = W + (size_t)e * IN_LEN;
        const float* srow = s_lds + o * IN_LEN;
        float a = 0.f;
#pragma unroll
        for (int i = 0; i < IN_LEN; ++i) a = fmaf(wrow[i], srow[i], a);
        u[e] = a;
    }
    __syncthreads();

    // squash scale per o
    if (tid < OUT_CAPS) {
        float ns = 0.f;
#pragma unroll
        for (int l = 0; l < OUT_LEN; ++l) { const float v = u[tid * OUT_LEN + l]; ns = fmaf(v, v, ns); }
        scale[tid] = sqrtf(ns) / (1.f + ns);
    }
    __syncthreads();

    if (final_iter) {
        for (int e = tid; e < OUT_CAPS * OUT_LEN; e += 256)
            out[(size_t)b * OUT_CAPS * OUT_LEN + e] = u[e] * scale[e >> 5];
    } else {
        for (int e = tid; e < OUT_CAPS * IN_LEN; e += 256) {
            const int o = e >> 5, i = e & 31;
            float a = 0.f;
#pragma unroll
            for (int l = 0; l < OUT_LEN; ++l)
                a = fmaf(W[((size_t)o * OUT_LEN + l) * IN_LEN + i], u[o * OUT_LEN + l], a);
            T[(size_t)b * OUT_CAPS * IN_LEN + e] += a * scale[o];
        }
    }
}

extern "C" void kernel_launch(void* const* d_in, const int* in_sizes, int n_in,
                              void* d_out, int out_size, void* d_ws, size_t ws_size,
                              hipStream_t stream) {
    const float* x = (const float*)d_in[0];   // [32,1152,32]
    const float* W = (const float*)d_in[1];   // [64,32,32]
    float* out = (float*)d_out;               // [32,64,32]

    float* T    = (float*)d_ws;                         // 32*64*32 floats (256 KB)
    float* part = T + (size_t)N_B * OUT_CAPS * IN_LEN;  // 32*16*64*32 floats (4 MB)
    int*   cnt  = (int*)(part + (size_t)N_B * NCHUNK * OUT_CAPS * IN_LEN); // 2*32 ints

    k_init   <<<N_B, 256, 0, stream>>>(x, W, T, cnt);
    k_pass_vt<<<N_B * NCHUNK, 256, 0, stream>>>(x, W, T, part, cnt,       out, 0); // iter 1
    k_pass_vt<<<N_B * NCHUNK, 256, 0, stream>>>(x, W, T, part, cnt + N_B, out, 1); // iter 2
}

// Round 2
// 164.749 us; speedup vs baseline: 1.6491x; 1.6491x over previous
//
#include <hip/hip_runtime.h>
#include <math.h>

// CapsuleLinear dynamic routing, `priors` never materialized.
//   s[b,o,i]   = sum_n prob[b,o,n] * x[b,n,i]
//   out[b,o,l] = sum_i W[o,l,i] * s[b,o,i]
//   logits[b,o,n] = x[b,n,:] . T[b,o,:],  T accumulates t_r[o,i] = sum_l W[o,l,i]*v_r[o,l]
// Chain: k_init -> k_pass -> k_vt -> k_pass -> k_vt(final)
//
// R2: k_pass rebuilt. R1 post-mortem showed VGPR_Count=52 for a kernel with
// ~100 floats of lane-private state: the compiler rematerialized the T-row as
// per-FMA global loads -> ~300cy/FMA serial chain (VALUBusy 4.4%). New
// structure has NO lane-private loop-invariant arrays:
//   A: logits via i-outer loop, T from padded LDS (2-way, free), x from a
//      transposed LDS tile via broadcast b128 reads, 18 indep fma chains.
//   B: 18 interleaved lane-softmaxes (ILP hides shuffle latency).
//   C: s[32] accumulators (must stay in regs) + broadcast row reads.
//   Flush: per-wave partial straight to global (no 32KB LDS reduce, no
//   64-way bank conflicts); k_vt sums 64 sub-partials.
// R1's ticket/threadfence fusion reverted (device fences on non-coherent
// XCD L2s forced HBM round-trips; 111us/pass).

#define N_B      32
#define IN_CAPS  1152
#define IN_LEN   32
#define OUT_CAPS 64
#define OUT_LEN  32

#define NCHUNK 16                    // n-chunks per batch -> 32*16 = 512 blocks
#define NPB    (IN_CAPS / NCHUNK)    // 72 n per block
#define PASS_WAVES 4                 // 256-thread blocks
#define NPW    (NPB / PASS_WAVES)    // 18 n per wave
#define NPART  (NCHUNK * PASS_WAVES) // 64 sub-partials per batch

// ---------------------------------------------------------------------------
// k_init: s0[i] = (1/64) sum_n x[b,n,i]; u = W@s0; v0 = squash(u); T = W^T@v0
// ---------------------------------------------------------------------------
__global__ __launch_bounds__(256) void k_init(const float* __restrict__ x,
                                              const float* __restrict__ W,
                                              float* __restrict__ T) {
    const int b   = blockIdx.x;
    const int tid = threadIdx.x;
    const float* xb = x + (size_t)b * IN_CAPS * IN_LEN;

    // --- reduce x over n (coalesced float4) ---
    __shared__ float4 red4[32][8];
    {
        const int q = tid & 7;        // float4 column (8 per row of 32)
        const int g = tid >> 3;       // 0..31 n-offset
        float4 acc = make_float4(0.f, 0.f, 0.f, 0.f);
        for (int n = g; n < IN_CAPS; n += 32) {
            const float4 v = *(const float4*)(xb + n * IN_LEN + q * 4);
            acc.x += v.x; acc.y += v.y; acc.z += v.z; acc.w += v.w;
        }
        red4[g][q] = acc;
    }
    __syncthreads();
    __shared__ float s0[IN_LEN];
    if (tid < 8) {
        float4 v = make_float4(0.f, 0.f, 0.f, 0.f);
        for (int g = 0; g < 32; ++g) {
            const float4 r = red4[g][tid];
            v.x += r.x; v.y += r.y; v.z += r.z; v.w += r.w;
        }
        const float inv = 1.f / 64.f;   // uniform softmax prob at r=0
        s0[tid * 4 + 0] = v.x * inv;
        s0[tid * 4 + 1] = v.y * inv;
        s0[tid * 4 + 2] = v.z * inv;
        s0[tid * 4 + 3] = v.w * inv;
    }
    __syncthreads();

    // --- u[o][l] = sum_i W[o,l,i] * s0[i] ---
    __shared__ float u[OUT_CAPS * OUT_LEN];
    for (int e = tid; e < OUT_CAPS * OUT_LEN; e += 256) {
        const float* wrow = W + (size_t)e * IN_LEN;
        float a = 0.f;
#pragma unroll
        for (int i = 0; i < IN_LEN; ++i) a = fmaf(wrow[i], s0[i], a);
        u[e] = a;
    }
    __syncthreads();

    // --- squash scale per o ---
    __shared__ float scale[OUT_CAPS];
    if (tid < OUT_CAPS) {
        float ns = 0.f;
#pragma unroll
        for (int l = 0; l < OUT_LEN; ++l) { const float v = u[tid * OUT_LEN + l]; ns = fmaf(v, v, ns); }
        scale[tid] = sqrtf(ns) / (1.f + ns);
    }
    __syncthreads();

    // --- T[b,o,i] = sum_l W[o,l,i] * (u[o,l]*scale[o]) ---
    for (int e = tid; e < OUT_CAPS * IN_LEN; e += 256) {
        const int o = e >> 5, i = e & 31;
        float a = 0.f;
#pragma unroll
        for (int l = 0; l < OUT_LEN; ++l)
            a = fmaf(W[((size_t)o * OUT_LEN + l) * IN_LEN + i], u[o * OUT_LEN + l], a);
        T[(size_t)b * OUT_CAPS * IN_LEN + e] = a * scale[o];
    }
}

// ---------------------------------------------------------------------------
// k_pass: per (b, n-chunk): logits = x.T (lane = o), softmax over lanes,
//         per-wave s[o,i] = sum_n prob*x -> part[b,c,w,:]
// ---------------------------------------------------------------------------
__global__ __launch_bounds__(256, 4) void k_pass(const float* __restrict__ x,
                                                 const float* __restrict__ T,
                                                 float* __restrict__ part) {
    const int b    = blockIdx.x >> 4;     // / NCHUNK
    const int c    = blockIdx.x & (NCHUNK - 1);
    const int tid  = threadIdx.x;
    const int lane = tid & 63;            // = output capsule o
    const int wave = __builtin_amdgcn_readfirstlane(tid >> 6);

    __shared__ float T_lds[OUT_CAPS * 33];                  // padded rows: 2-way reads
    __shared__ __align__(16) float x_row[NPB * IN_LEN];     // [n][i], row-major
    __shared__ __align__(16) float x_col[IN_LEN * 80];      // [i][w*20 + idx], transposed

    // ---- stage T (8 KB) into padded LDS ----
    {
        const float4* T4 = (const float4*)(T + (size_t)b * OUT_CAPS * IN_LEN);
        for (int e = tid; e < OUT_CAPS * IN_LEN / 4; e += 256) {
            const float4 v = T4[e];
            const int o = e >> 3, q = e & 7;
            float* d = &T_lds[o * 33 + q * 4];
            d[0] = v.x; d[1] = v.y; d[2] = v.z; d[3] = v.w;
        }
    }
    // ---- stage x chunk (9 KB): row-major copy + transposed copy ----
    {
        const float4* X4 = (const float4*)(x + ((size_t)b * IN_CAPS + c * NPB) * IN_LEN);
        for (int e = tid; e < NPB * IN_LEN / 4; e += 256) {
            const float4 v = X4[e];
            ((float4*)x_row)[e] = v;
            const int n = e >> 3, q = e & 7;
            const int wq = n / NPW, idx = n - wq * NPW;     // wave slot, 20-wide padded
            float* d = &x_col[(q * 4) * 80 + wq * 20 + idx];
            d[0] = v.x; d[80] = v.y; d[160] = v.z; d[240] = v.w;
        }
    }
    __syncthreads();

    // ---- Stage A: acc[n] = logit for (n = wave*18+n, o = lane) ----
    float acc[NPW];
#pragma unroll
    for (int n = 0; n < NPW; ++n) acc[n] = 0.f;

#define FMA4A(v, k0) \
    acc[k0+0] = fmaf(tv, (v).x, acc[k0+0]); \
    acc[k0+1] = fmaf(tv, (v).y, acc[k0+1]); \
    acc[k0+2] = fmaf(tv, (v).z, acc[k0+2]); \
    acc[k0+3] = fmaf(tv, (v).w, acc[k0+3]);

#pragma unroll
    for (int i = 0; i < IN_LEN; ++i) {
        const float tv = T_lds[lane * 33 + i];                       // 2-way, free
        const float4* xr = (const float4*)&x_col[i * 80 + wave * 20]; // uniform: broadcast
        const float4 a0 = xr[0], a1 = xr[1], a2 = xr[2], a3 = xr[3], a4 = xr[4];
        FMA4A(a0, 0) FMA4A(a1, 4) FMA4A(a2, 8) FMA4A(a3, 12)
        acc[16] = fmaf(tv, a4.x, acc[16]);
        acc[17] = fmaf(tv, a4.y, acc[17]);
    }
#undef FMA4A

    // ---- Stage B: 18 interleaved softmaxes over the 64 lanes ----
    float prob[NPW];
#pragma unroll
    for (int n = 0; n < NPW; ++n) {
        float m = acc[n];
#pragma unroll
        for (int off = 32; off >= 1; off >>= 1) m = fmaxf(m, __shfl_xor(m, off, 64));
        const float p = __expf(acc[n] - m);
        float ssum = p;
#pragma unroll
        for (int off = 32; off >= 1; off >>= 1) ssum += __shfl_xor(ssum, off, 64);
        prob[n] = p / ssum;
    }

    // ---- Stage C: s[i] = sum_n prob[n] * x[n][i] (broadcast row reads) ----
    float s[IN_LEN];
#pragma unroll
    for (int i = 0; i < IN_LEN; ++i) s[i] = 0.f;

#pragma unroll
    for (int n = 0; n < NPW; ++n) {
        const float pn = prob[n];
        const float4* xr = (const float4*)&x_row[(wave * NPW + n) * IN_LEN]; // uniform
#pragma unroll
        for (int q = 0; q < 8; ++q) {
            const float4 v = xr[q];
            s[q * 4 + 0] = fmaf(pn, v.x, s[q * 4 + 0]);
            s[q * 4 + 1] = fmaf(pn, v.y, s[q * 4 + 1]);
            s[q * 4 + 2] = fmaf(pn, v.z, s[q * 4 + 2]);
            s[q * 4 + 3] = fmaf(pn, v.w, s[q * 4 + 3]);
        }
    }

    // ---- flush: per-wave partial straight to global (L2 merges the 128B row) ----
    {
        float4* dst = (float4*)(part +
            ((((size_t)b * NCHUNK + c) * PASS_WAVES + wave) * OUT_CAPS + lane) * IN_LEN);
#pragma unroll
        for (int q = 0; q < 8; ++q)
            dst[q] = make_float4(s[4 * q], s[4 * q + 1], s[4 * q + 2], s[4 * q + 3]);
    }
}

// ---------------------------------------------------------------------------
// k_vt: s = sum of 64 sub-partials; u = W@s; squash; final ? out : T += W^T@v
// ---------------------------------------------------------------------------
__global__ __launch_bounds__(256) void k_vt(const float* __restrict__ W,
                                            const float* __restrict__ part,
                                            float* __restrict__ T,
                                            float* __restrict__ out,
                                            int final_iter) {
    const int b   = blockIdx.x;
    const int tid = threadIdx.x;

    __shared__ float s_lds[OUT_CAPS * IN_LEN];
    {
        const float4* pb4 = (const float4*)(part + (size_t)b * NPART * OUT_CAPS * IN_LEN);
        for (int e = tid; e < OUT_CAPS * IN_LEN / 4; e += 256) {
            float4 acc = make_float4(0.f, 0.f, 0.f, 0.f);
#pragma unroll 8
            for (int c = 0; c < NPART; ++c) {
                const float4 v = pb4[c * (OUT_CAPS * IN_LEN / 4) + e];
                acc.x += v.x; acc.y += v.y; acc.z += v.z; acc.w += v.w;
            }
            ((float4*)s_lds)[e] = acc;
        }
    }
    __syncthreads();

    __shared__ float u[OUT_CAPS * OUT_LEN];
    for (int e = tid; e < OUT_CAPS * OUT_LEN; e += 256) {
        const int o = e >> 5;
        const float* wrow = W + (size_t)e * IN_LEN;
        const float* srow = s_lds + o * IN_LEN;
        float a = 0.f;
#pragma unroll
        for (int i = 0; i < IN_LEN; ++i) a = fmaf(wrow[i], srow[i], a);
        u[e] = a;
    }
    __syncthreads();

    __shared__ float scale[OUT_CAPS];
    if (tid < OUT_CAPS) {
        float ns = 0.f;
#pragma unroll
        for (int l = 0; l < OUT_LEN; ++l) { const float v = u[tid * OUT_LEN + l]; ns = fmaf(v, v, ns); }
        scale[tid] = sqrtf(ns) / (1.f + ns);
    }
    __syncthreads();

    if (final_iter) {
        for (int e = tid; e < OUT_CAPS * OUT_LEN; e += 256)
            out[(size_t)b * OUT_CAPS * OUT_LEN + e] = u[e] * scale[e >> 5];
    } else {
        for (int e = tid; e < OUT_CAPS * IN_LEN; e += 256) {
            const int o = e >> 5, i = e & 31;
            float a = 0.f;
#pragma unroll
            for (int l = 0; l < OUT_LEN; ++l)
                a = fmaf(W[((size_t)o * OUT_LEN + l) * IN_LEN + i], u[o * OUT_LEN + l], a);
            T[(size_t)b * OUT_CAPS * IN_LEN + e] += a * scale[o];
        }
    }
}

extern "C" void kernel_launch(void* const* d_in, const int* in_sizes, int n_in,
                              void* d_out, int out_size, void* d_ws, size_t ws_size,
                              hipStream_t stream) {
    const float* x = (const float*)d_in[0];   // [32,1152,32]
    const float* W = (const float*)d_in[1];   // [64,32,32]
    float* out = (float*)d_out;               // [32,64,32]

    float* T    = (float*)d_ws;                         // 32*64*32 floats (256 KB)
    float* part = T + (size_t)N_B * OUT_CAPS * IN_LEN;  // 32*64*64*32 floats (16 MB)

    k_init<<<N_B, 256, 0, stream>>>(x, W, T);
    k_pass<<<N_B * NCHUNK, 256, 0, stream>>>(x, T, part);        // routing iter 1
    k_vt  <<<N_B, 256, 0, stream>>>(W, part, T, out, 0);
    k_pass<<<N_B * NCHUNK, 256, 0, stream>>>(x, T, part);        // routing iter 2
    k_vt  <<<N_B, 256, 0, stream>>>(W, part, T, out, 1);
}

// Round 4
// 131.587 us; speedup vs baseline: 2.0646x; 1.2520x over previous
//
#include <hip/hip_runtime.h>
#include <math.h>

// CapsuleLinear dynamic routing, `priors` never materialized.
//   s[b,o,i]   = sum_n prob[b,o,n] * x[b,n,i]
//   out[b,o,l] = sum_i W[o,l,i] * s[b,o,i]
//   logits[b,o,n] = x[b,n,:] . T[b,o,:],  T accumulates t_r[o,i] = sum_l W[o,l,i]*v_r[o,l]
// Chain: k_init -> k_pass -> k_vt -> k_pass -> k_vt(final)
//
// R4: k_pass main loop with (almost) no DS-pipe ops, using only low-risk
// constructs (R3's inline-asm s_load + exotic DPP bcast variant NaN'd):
//   - x rows: same-address VMEM broadcast float4 loads (TA coalesces
//     same-address across lanes into one request; chunk is L1-resident).
//     Full unroll -> base+imm addressing, compiler pipelines via vmcnt.
//   - softmax: simple DPP butterfly (full masks, bound_ctrl=true) for the
//     within-row-16 steps + R2-proven __shfl_xor for offsets 16/32.
//     216 -> 72 DS ops/wave.
//   - T row pinned in VGPRs via empty-asm keep-alive (R1 demotion guard).
//   - k_init / k_vt byte-identical to the R0-proven versions.

#define N_B      32
#define IN_CAPS  1152
#define IN_LEN   32
#define OUT_CAPS 64
#define OUT_LEN  32

#define NCHUNK 16                    // n-chunks per batch -> 32*16 = 512 blocks
#define NPB    (IN_CAPS / NCHUNK)    // 72 n per block
#define PASS_WAVES 4                 // 256-thread blocks
#define NPW    (NPB / PASS_WAVES)    // 18 n per wave

// DPP helper: butterfly step, all lanes valid, zero-fill semantics unused.
#define DPPV(v, ctrl) \
    __int_as_float(__builtin_amdgcn_update_dpp(0, __float_as_int(v), ctrl, 0xF, 0xF, true))

__device__ __forceinline__ float wave_max(float v) {
    v = fmaxf(v, DPPV(v, 0xB1));         // quad_perm xor1
    v = fmaxf(v, DPPV(v, 0x4E));         // quad_perm xor2
    v = fmaxf(v, DPPV(v, 0x141));        // row_half_mirror (xor4 within 8)
    v = fmaxf(v, DPPV(v, 0x140));        // row_mirror (xor8 within 16)
    v = fmaxf(v, __shfl_xor(v, 16, 64)); // cross-row, R2-proven path
    v = fmaxf(v, __shfl_xor(v, 32, 64));
    return v;
}
__device__ __forceinline__ float wave_sum(float v) {
    v += DPPV(v, 0xB1);
    v += DPPV(v, 0x4E);
    v += DPPV(v, 0x141);
    v += DPPV(v, 0x140);
    v += __shfl_xor(v, 16, 64);
    v += __shfl_xor(v, 32, 64);
    return v;
}

// ---------------------------------------------------------------------------
// k_init: s0[i] = (1/64) sum_n x[b,n,i]; u = W@s0; v0 = squash(u); T = W^T@v0
// (byte-identical to the R0-proven version)
// ---------------------------------------------------------------------------
__global__ __launch_bounds__(256) void k_init(const float* __restrict__ x,
                                              const float* __restrict__ W,
                                              float* __restrict__ T) {
    const int b   = blockIdx.x;
    const int tid = threadIdx.x;
    const float* xb = x + (size_t)b * IN_CAPS * IN_LEN;

    __shared__ float4 red4[32][8];
    {
        const int q = tid & 7;        // float4 column (8 per row of 32)
        const int g = tid >> 3;       // 0..31 n-offset
        float4 acc = make_float4(0.f, 0.f, 0.f, 0.f);
        for (int n = g; n < IN_CAPS; n += 32) {
            const float4 v = *(const float4*)(xb + n * IN_LEN + q * 4);
            acc.x += v.x; acc.y += v.y; acc.z += v.z; acc.w += v.w;
        }
        red4[g][q] = acc;
    }
    __syncthreads();
    __shared__ float s0[IN_LEN];
    if (tid < 8) {
        float4 v = make_float4(0.f, 0.f, 0.f, 0.f);
        for (int g = 0; g < 32; ++g) {
            const float4 r = red4[g][tid];
            v.x += r.x; v.y += r.y; v.z += r.z; v.w += r.w;
        }
        const float inv = 1.f / 64.f;   // uniform softmax prob at r=0
        s0[tid * 4 + 0] = v.x * inv;
        s0[tid * 4 + 1] = v.y * inv;
        s0[tid * 4 + 2] = v.z * inv;
        s0[tid * 4 + 3] = v.w * inv;
    }
    __syncthreads();

    __shared__ float u[OUT_CAPS * OUT_LEN];
    for (int e = tid; e < OUT_CAPS * OUT_LEN; e += 256) {
        const float* wrow = W + (size_t)e * IN_LEN;
        float a = 0.f;
#pragma unroll
        for (int i = 0; i < IN_LEN; ++i) a = fmaf(wrow[i], s0[i], a);
        u[e] = a;
    }
    __syncthreads();

    __shared__ float scale[OUT_CAPS];
    if (tid < OUT_CAPS) {
        float ns = 0.f;
#pragma unroll
        for (int l = 0; l < OUT_LEN; ++l) { const float v = u[tid * OUT_LEN + l]; ns = fmaf(v, v, ns); }
        scale[tid] = sqrtf(ns) / (1.f + ns);
    }
    __syncthreads();

    for (int e = tid; e < OUT_CAPS * IN_LEN; e += 256) {
        const int o = e >> 5, i = e & 31;
        float a = 0.f;
#pragma unroll
        for (int l = 0; l < OUT_LEN; ++l)
            a = fmaf(W[((size_t)o * OUT_LEN + l) * IN_LEN + i], u[o * OUT_LEN + l], a);
        T[(size_t)b * OUT_CAPS * IN_LEN + e] = a * scale[o];
    }
}

// ---------------------------------------------------------------------------
// k_pass: per (b, n-chunk, wave): 18 n's. x rows via same-address broadcast
//         VMEM loads; T row pinned in VGPRs; softmax via DPP+shfl.
// ---------------------------------------------------------------------------
__global__ __launch_bounds__(256, 2) void k_pass(const float* __restrict__ x,
                                                 const float* __restrict__ T,
                                                 float* __restrict__ part) {
    const int b    = blockIdx.x >> 4;     // / NCHUNK
    const int c    = blockIdx.x & (NCHUNK - 1);
    const int tid  = threadIdx.x;
    const int lane = tid & 63;            // = output capsule o
    const int wave = __builtin_amdgcn_readfirstlane(tid >> 6);

    // T row (lane = o) into registers, pinned against rematerialization
    float t[IN_LEN];
    {
        const float4* Trow4 = (const float4*)(T + ((size_t)b * OUT_CAPS + lane) * IN_LEN);
#pragma unroll
        for (int q = 0; q < 8; ++q) {
            const float4 v = Trow4[q];
            t[4 * q] = v.x; t[4 * q + 1] = v.y; t[4 * q + 2] = v.z; t[4 * q + 3] = v.w;
        }
    }
    asm volatile("" : "+v"(t[0]), "+v"(t[1]), "+v"(t[2]), "+v"(t[3]),
                      "+v"(t[4]), "+v"(t[5]), "+v"(t[6]), "+v"(t[7]),
                      "+v"(t[8]), "+v"(t[9]), "+v"(t[10]), "+v"(t[11]),
                      "+v"(t[12]), "+v"(t[13]), "+v"(t[14]), "+v"(t[15]));
    asm volatile("" : "+v"(t[16]), "+v"(t[17]), "+v"(t[18]), "+v"(t[19]),
                      "+v"(t[20]), "+v"(t[21]), "+v"(t[22]), "+v"(t[23]),
                      "+v"(t[24]), "+v"(t[25]), "+v"(t[26]), "+v"(t[27]),
                      "+v"(t[28]), "+v"(t[29]), "+v"(t[30]), "+v"(t[31]));

    float s[IN_LEN];
#pragma unroll
    for (int i = 0; i < IN_LEN; ++i) s[i] = 0.f;

    const float* xw = x + ((size_t)b * IN_CAPS + c * NPB + wave * NPW) * IN_LEN;

#define L4(acc, R, k) \
    acc = fmaf((R).x, t[k],     acc); acc = fmaf((R).y, t[k + 1], acc); \
    acc = fmaf((R).z, t[k + 2], acc); acc = fmaf((R).w, t[k + 3], acc);
#define S4(R, k) \
    s[k]     = fmaf(prob, (R).x, s[k]);     s[k + 1] = fmaf(prob, (R).y, s[k + 1]); \
    s[k + 2] = fmaf(prob, (R).z, s[k + 2]); s[k + 3] = fmaf(prob, (R).w, s[k + 3]);

#pragma unroll
    for (int j = 0; j < NPW; ++j) {
        const float4* xr = (const float4*)(xw + j * IN_LEN);  // wave-uniform addr
        const float4 r0 = xr[0], r1 = xr[1], r2 = xr[2], r3 = xr[3],
                     r4 = xr[4], r5 = xr[5], r6 = xr[6], r7 = xr[7];

        float l0 = 0.f, l1 = 0.f, l2 = 0.f, l3 = 0.f;
        L4(l0, r0, 0)  L4(l1, r1, 4)  L4(l2, r2, 8)  L4(l3, r3, 12)
        L4(l0, r4, 16) L4(l1, r5, 20) L4(l2, r6, 24) L4(l3, r7, 28)
        const float logit = (l0 + l1) + (l2 + l3);

        const float m = wave_max(logit);
        const float p = __expf(logit - m);
        const float S = wave_sum(p);
        const float prob = p * __builtin_amdgcn_rcpf(S);

        S4(r0, 0)  S4(r1, 4)  S4(r2, 8)  S4(r3, 12)
        S4(r4, 16) S4(r5, 20) S4(r6, 24) S4(r7, 28)
    }
#undef L4
#undef S4

    // ---- flush: padded LDS (stride 36 floats, 16B-aligned), block reduce ----
    __shared__ __align__(16) float sp[PASS_WAVES][OUT_CAPS][36];   // 36 KB
    {
        float4* dst = (float4*)&sp[wave][lane][0];
#pragma unroll
        for (int q = 0; q < 8; ++q)
            dst[q] = make_float4(s[4 * q], s[4 * q + 1], s[4 * q + 2], s[4 * q + 3]);
    }
    __syncthreads();
    {
        float4* pb4 = (float4*)(part + ((size_t)b * NCHUNK + c) * OUT_CAPS * IN_LEN);
        for (int e = tid; e < OUT_CAPS * IN_LEN / 4; e += 256) {
            const int o = e >> 3, q4 = (e & 7) * 4;
            const float4 a0 = *(const float4*)&sp[0][o][q4];
            const float4 a1 = *(const float4*)&sp[1][o][q4];
            const float4 a2 = *(const float4*)&sp[2][o][q4];
            const float4 a3 = *(const float4*)&sp[3][o][q4];
            pb4[e] = make_float4(a0.x + a1.x + a2.x + a3.x,
                                 a0.y + a1.y + a2.y + a3.y,
                                 a0.z + a1.z + a2.z + a3.z,
                                 a0.w + a1.w + a2.w + a3.w);
        }
    }
}

// ---------------------------------------------------------------------------
// k_vt: s = sum_c part (16 slabs); u = W@s; squash; final ? out : T += W^T@v
// (byte-identical to the R0-proven version)
// ---------------------------------------------------------------------------
__global__ __launch_bounds__(256) void k_vt(const float* __restrict__ W,
                                            const float* __restrict__ part,
                                            float* __restrict__ T,
                                            float* __restrict__ out,
                                            int final_iter) {
    const int b   = blockIdx.x;
    const int tid = threadIdx.x;

    __shared__ float s_lds[OUT_CAPS * IN_LEN];
    {
        const float4* pb4 = (const float4*)(part + (size_t)b * NCHUNK * OUT_CAPS * IN_LEN);
        for (int e = tid; e < OUT_CAPS * IN_LEN / 4; e += 256) {
            float4 acc = make_float4(0.f, 0.f, 0.f, 0.f);
#pragma unroll
            for (int c = 0; c < NCHUNK; ++c) {
                const float4 v = pb4[c * (OUT_CAPS * IN_LEN / 4) + e];
                acc.x += v.x; acc.y += v.y; acc.z += v.z; acc.w += v.w;
            }
            ((float4*)s_lds)[e] = acc;
        }
    }
    __syncthreads();

    __shared__ float u[OUT_CAPS * OUT_LEN];
    for (int e = tid; e < OUT_CAPS * OUT_LEN; e += 256) {
        const int o = e >> 5;
        const float* wrow = W + (size_t)e * IN_LEN;
        const float* srow = s_lds + o * IN_LEN;
        float a = 0.f;
#pragma unroll
        for (int i = 0; i < IN_LEN; ++i) a = fmaf(wrow[i], srow[i], a);
        u[e] = a;
    }
    __syncthreads();

    __shared__ float scale[OUT_CAPS];
    if (tid < OUT_CAPS) {
        float ns = 0.f;
#pragma unroll
        for (int l = 0; l < OUT_LEN; ++l) { const float v = u[tid * OUT_LEN + l]; ns = fmaf(v, v, ns); }
        scale[tid] = sqrtf(ns) / (1.f + ns);
    }
    __syncthreads();

    if (final_iter) {
        for (int e = tid; e < OUT_CAPS * OUT_LEN; e += 256)
            out[(size_t)b * OUT_CAPS * OUT_LEN + e] = u[e] * scale[e >> 5];
    } else {
        for (int e = tid; e < OUT_CAPS * IN_LEN; e += 256) {
            const int o = e >> 5, i = e & 31;
            float a = 0.f;
#pragma unroll
            for (int l = 0; l < OUT_LEN; ++l)
                a = fmaf(W[((size_t)o * OUT_LEN + l) * IN_LEN + i], u[o * OUT_LEN + l], a);
            T[(size_t)b * OUT_CAPS * IN_LEN + e] += a * scale[o];
        }
    }
}

extern "C" void kernel_launch(void* const* d_in, const int* in_sizes, int n_in,
                              void* d_out, int out_size, void* d_ws, size_t ws_size,
                              hipStream_t stream) {
    const float* x = (const float*)d_in[0];   // [32,1152,32]
    const float* W = (const float*)d_in[1];   // [64,32,32]
    float* out = (float*)d_out;               // [32,64,32]

    float* T    = (float*)d_ws;                         // 32*64*32 floats (256 KB)
    float* part = T + (size_t)N_B * OUT_CAPS * IN_LEN;  // 32*16*64*32 floats (4 MB)

    k_init<<<N_B, 256, 0, stream>>>(x, W, T);
    k_pass<<<N_B * NCHUNK, 256, 0, stream>>>(x, T, part);        // routing iter 1
    k_vt  <<<N_B, 256, 0, stream>>>(W, part, T, out, 0);
    k_pass<<<N_B * NCHUNK, 256, 0, stream>>>(x, T, part);        // routing iter 2
    k_vt  <<<N_B, 256, 0, stream>>>(W, part, T, out, 1);
}